// Round 12
// baseline (788.605 us; speedup 1.0000x reference)
//
#include <hip/hip_runtime.h>
#include <hip/hip_bf16.h>

typedef __attribute__((ext_vector_type(8))) short s16x8;
typedef __attribute__((ext_vector_type(4))) short s16x4;
typedef __attribute__((ext_vector_type(4))) float f32x4;

#define GAS __attribute__((address_space(1)))
#define LAS __attribute__((address_space(3)))

#define WAITV(N) asm volatile("s_waitcnt vmcnt(" #N ")" ::: "memory")
#define WAITL() asm volatile("s_waitcnt lgkmcnt(0)" ::: "memory")
#define BAR() __builtin_amdgcn_s_barrier()

__device__ __forceinline__ float b2f(unsigned short u) {
  union { unsigned int i; float f; } x; x.i = ((unsigned int)u) << 16; return x.f;
}
__device__ __forceinline__ unsigned short f2b(float f) {
  union { float f; unsigned int i; } x; x.f = f;
  unsigned int r = x.i + 0x7fffu + ((x.i >> 16) & 1u);
  return (unsigned short)(r >> 16);
}

// async global->LDS, 16B per lane; lds dest is wave-uniform base + lane*16
__device__ __forceinline__ void gl16(const unsigned short* g, unsigned short* l) {
  __builtin_amdgcn_global_load_lds((const GAS unsigned int*)g,
                                   (LAS unsigned int*)l, 16, 0, 0);
}

// ---------------- weight packing ----------------
__global__ __launch_bounds__(256) void pack_qkv_k(const float* __restrict__ wq,
                                                  const float* __restrict__ wk,
                                                  const float* __restrict__ wv,
                                                  unsigned short* __restrict__ dst) {
  int idx = blockIdx.x * 256 + threadIdx.x;   // n*512 + c
  int n = idx >> 9, c = idx & 511;
  int sel = n >> 9;
  int hn = n & 511;
  const float* src = sel == 0 ? wq : (sel == 1 ? wk : wv);
  float v = src[((hn >> 6) << 15) + (c << 6) + (hn & 63)];  // wq[h][c][d]
  dst[idx] = f2b(v);
}

// dst[n][k] = src[k][n], src is (K,N) row-major
__global__ __launch_bounds__(256) void pack_T_k(const float* __restrict__ src,
                                                unsigned short* __restrict__ dst,
                                                int K, int N) {
  int idx = blockIdx.x * 256 + threadIdx.x;
  int n = idx / K, k = idx % K;
  dst[idx] = f2b(src[(long long)k * N + n]);
}

// ---------------- layernorm (wave per row, C=512), fp32 input ----------------
__global__ __launch_bounds__(256) void ln_k(const float* __restrict__ in,
                                            const float* __restrict__ g,
                                            const float* __restrict__ bb,
                                            unsigned short* __restrict__ out) {
  int row = blockIdx.x * 4 + (threadIdx.x >> 6);
  int lane = threadIdx.x & 63;
  const float* p = in + (size_t)row * 512 + lane * 8;
  f32x4 a = *(const f32x4*)p;
  f32x4 b = *(const f32x4*)(p + 4);
  float vals[8] = {a.x, a.y, a.z, a.w, b.x, b.y, b.z, b.w};
  float s = 0.f, q = 0.f;
#pragma unroll
  for (int i = 0; i < 8; i++) { s += vals[i]; q += vals[i] * vals[i]; }
#pragma unroll
  for (int off = 1; off < 64; off <<= 1) {
    s += __shfl_xor(s, off);
    q += __shfl_xor(q, off);
  }
  float mean = s * (1.0f / 512.0f);
  float rstd = rsqrtf(q * (1.0f / 512.0f) - mean * mean + 1e-5f);
  const float* gp = g + lane * 8;
  const float* bp = bb + lane * 8;
  s16x8 o;
#pragma unroll
  for (int i = 0; i < 8; i++) o[i] = (short)f2b((vals[i] - mean) * rstd * gp[i] + bp[i]);
  *(s16x8*)(out + (size_t)row * 512 + lane * 8) = o;
}

// ---------------- layernorm, bf16 input ----------------
__global__ __launch_bounds__(256) void ln_b_k(const unsigned short* __restrict__ in,
                                              const float* __restrict__ g,
                                              const float* __restrict__ bb,
                                              unsigned short* __restrict__ out) {
  int row = blockIdx.x * 4 + (threadIdx.x >> 6);
  int lane = threadIdx.x & 63;
  s16x8 v8 = *(const s16x8*)(in + (size_t)row * 512 + lane * 8);
  float vals[8];
#pragma unroll
  for (int i = 0; i < 8; i++) vals[i] = b2f((unsigned short)v8[i]);
  float s = 0.f, q = 0.f;
#pragma unroll
  for (int i = 0; i < 8; i++) { s += vals[i]; q += vals[i] * vals[i]; }
#pragma unroll
  for (int off = 1; off < 64; off <<= 1) {
    s += __shfl_xor(s, off);
    q += __shfl_xor(q, off);
  }
  float mean = s * (1.0f / 512.0f);
  float rstd = rsqrtf(q * (1.0f / 512.0f) - mean * mean + 1e-5f);
  const float* gp = g + lane * 8;
  const float* bp = bb + lane * 8;
  s16x8 o;
#pragma unroll
  for (int i = 0; i < 8; i++) o[i] = (short)f2b((vals[i] - mean) * rstd * gp[i] + bp[i]);
  *(s16x8*)(out + (size_t)row * 512 + lane * 8) = o;
}

// ---------------- attention (one wave per (b,h); T=16, D=64) ----------------
__global__ __launch_bounds__(256) void attn_k(const unsigned short* __restrict__ qkv,
                                              unsigned short* __restrict__ o) {
  int w = (blockIdx.x << 2) + (threadIdx.x >> 6);
  int lane = threadIdx.x & 63;
  int b = w >> 3, h = w & 7;
  int t = lane >> 2, p = lane & 3;   // 4 lanes per query row, 16 d's each

  size_t rowq = (size_t)(b * 16 + t) * 1536 + h * 64 + p * 16;
  float q[16];
  {
    s16x8 q0 = *(const s16x8*)(qkv + rowq);
    s16x8 q1 = *(const s16x8*)(qkv + rowq + 8);
#pragma unroll
    for (int i = 0; i < 8; i++) {
      q[i] = b2f((unsigned short)q0[i]) * 0.125f;
      q[8 + i] = b2f((unsigned short)q1[i]) * 0.125f;
    }
  }
  float lg[16];
  size_t kbase = (size_t)(b * 16) * 1536 + 512 + h * 64 + p * 16;
#pragma unroll
  for (int s = 0; s < 16; s++) {
    const unsigned short* kp = qkv + kbase + (size_t)s * 1536;
    s16x8 k0 = *(const s16x8*)kp;
    s16x8 k1 = *(const s16x8*)(kp + 8);
    float d = 0.f;
#pragma unroll
    for (int i = 0; i < 8; i++)
      d += q[i] * b2f((unsigned short)k0[i]) + q[8 + i] * b2f((unsigned short)k1[i]);
    d += __shfl_xor(d, 1);
    d += __shfl_xor(d, 2);
    lg[s] = d;
  }
  float mx = -1e30f;
#pragma unroll
  for (int s = 0; s < 16; s++)
    if (s <= t) mx = fmaxf(mx, lg[s]);
  float den = 0.f;
#pragma unroll
  for (int s = 0; s < 16; s++) {
    float e = (s <= t) ? __expf(lg[s] - mx) : 0.f;
    lg[s] = e;
    den += e;
  }
  float inv = 1.f / den;
  float acc[16] = {};
  size_t vbase = kbase + 512;
#pragma unroll
  for (int s = 0; s < 16; s++) {
    const unsigned short* vp = qkv + vbase + (size_t)s * 1536;
    s16x8 v0 = *(const s16x8*)vp;
    s16x8 v1 = *(const s16x8*)(vp + 8);
    float a = lg[s] * inv;
#pragma unroll
    for (int i = 0; i < 8; i++) {
      acc[i] += a * b2f((unsigned short)v0[i]);
      acc[8 + i] += a * b2f((unsigned short)v1[i]);
    }
  }
  size_t orow = (size_t)(b * 16 + t) * 512 + h * 64 + p * 16;
  s16x8 r0, r1;
#pragma unroll
  for (int i = 0; i < 8; i++) {
    r0[i] = (short)f2b(acc[i]);
    r1[i] = (short)f2b(acc[8 + i]);
  }
  *(s16x8*)(o + orow) = r0;
  *(s16x8*)(o + orow + 8) = r1;
}

// ---------------- bf16 MFMA GEMM: 256x256 tile, BK=32, 8 waves, 4-buf ring ----------------
// T3+T4 deep pipeline: 4 LDS buffers (4 x 32KB = 128KB), prefetch distance 3
// K-tiles (~1200 cy lookahead > ~900 cy HBM latency). Counted WAITV(12) =
// {t+1,t+2,t+3}x4 loads stay in flight (never 0 until 3-tile peeled tail).
// Per tile: 2 phases x {ds_read, setprio(1), 16 MFMA, setprio(0)} (T5 on a
// phase-split schedule). Source-side XOR swizzle (0 conflicts measured).
// Barriers: [stage(t+3)] WAITV BAR ph0 ph1 BAR  -- stage(t+3) overwrites
// buf[(t-1)&3] whose readers all passed the previous trailing barrier.
enum { EPI_BF16 = 0, EPI_RESF32 = 1, EPI_RELU_BF16 = 2, EPI_YB = 3, EPI_OUTB = 4 };

template <int EPI>
__global__ __launch_bounds__(512, 2) void gemm_bt(
    const unsigned short* __restrict__ A,   // (M, K) bf16
    const unsigned short* __restrict__ Bt,  // (N, K) bf16
    int K, int N, int nT,
    const float* __restrict__ bias, const void* __restrict__ res,
    float* __restrict__ outF, unsigned short* __restrict__ outB) {
  // buf b: A at b*32768, B at b*32768+16384 (bytes). Tile = 256 rows x 32 cols bf16.
  __shared__ __align__(16) unsigned char SM[131072];

  int tid = threadIdx.x;
  // XCD-chunked 1D swizzle, N-fastest tile order (grids are multiples of 8)
  int lid = ((int)blockIdx.x & 7) * ((int)gridDim.x >> 3) + ((int)blockIdx.x >> 3);
  int mBase = (lid / nT) * 256;
  int nBase = (lid % nT) * 256;

  int lane = tid & 63;
  int wid = tid >> 6;     // 0..7
  int wm = wid >> 2;      // 0..1 -> A rows wm*128..
  int wn = wid & 3;       // 0..3 -> B rows wn*64..
  int l15 = lane & 15;
  int s4 = lane >> 4;     // 0..3
  int lr4 = s4 * 4;
  int fc = ((s4 ^ ((l15 >> 1) & 3)) << 3);   // swizzled 8-elem slot for ds_read

  // staging: thread covers row tid>>2 (0..127), phys 16B slot tid&3;
  // source col pre-swizzled: LDS[r][p] = G[r][p ^ ((r>>1)&3)]
  int srow = tid >> 2;
  int scol = (((tid & 3) ^ ((tid >> 3) & 3)) << 3);
  const unsigned short* pa = A + (size_t)(mBase + srow) * K + scol;
  const unsigned short* pb = Bt + (size_t)(nBase + srow) * K + scol;
  size_t k128 = (size_t)128 * K;

  f32x4 acc[8][4] = {};

  auto stage = [&](int buf, int kt) {   // 4 gl16/thread = one 256x32 A tile + B tile
    unsigned short* dA = (unsigned short*)(SM + buf * 32768) + wid * 512;
    unsigned short* dB = (unsigned short*)(SM + buf * 32768 + 16384) + wid * 512;
    gl16(pa + kt, dA);                  // A rows 0..127
    gl16(pa + kt + k128, dA + 4096);    // A rows 128..255
    gl16(pb + kt, dB);
    gl16(pb + kt + k128, dB + 4096);
  };

  auto computeT = [&](int buf) {
    const unsigned short* hA = (const unsigned short*)(SM + buf * 32768) + wm * 4096;
    const unsigned short* hB = (const unsigned short*)(SM + buf * 32768 + 16384) + wn * 2048;
    s16x8 bfr[4], afr[4];
    // phase 0: B frags + A rows 0-63 of the wave's half
#pragma unroll
    for (int n = 0; n < 4; ++n)
      bfr[n] = *(const s16x8*)&hB[(n * 16 + l15) * 32 + fc];
#pragma unroll
    for (int m = 0; m < 4; ++m)
      afr[m] = *(const s16x8*)&hA[(m * 16 + l15) * 32 + fc];
    __builtin_amdgcn_s_setprio(1);
#pragma unroll
    for (int m = 0; m < 4; ++m)
#pragma unroll
      for (int n = 0; n < 4; ++n)
        acc[m][n] = __builtin_amdgcn_mfma_f32_16x16x32_bf16(afr[m], bfr[n], acc[m][n], 0, 0, 0);
    __builtin_amdgcn_s_setprio(0);
    // phase 1: A rows 64-127
#pragma unroll
    for (int m = 0; m < 4; ++m)
      afr[m] = *(const s16x8*)&hA[((m + 4) * 16 + l15) * 32 + fc];
    __builtin_amdgcn_s_setprio(1);
#pragma unroll
    for (int m = 0; m < 4; ++m)
#pragma unroll
      for (int n = 0; n < 4; ++n)
        acc[m + 4][n] = __builtin_amdgcn_mfma_f32_16x16x32_bf16(afr[m], bfr[n], acc[m + 4][n], 0, 0, 0);
    __builtin_amdgcn_s_setprio(0);
  };

  int NT = K >> 5;                       // K=512 -> 16, K=2048 -> 64 (always >= 4)
  stage(0, 0);
  stage(1, 32);
  stage(2, 64);
  for (int t = 0; t < NT - 3; ++t) {
    stage((t + 3) & 3, (t + 3) << 5);    // 16 in flight
    WAITV(12);                           // tile t's 4 landed; 12 stay in flight
    BAR();                               // cross-wave visibility of buf[t&3]
    computeT(t & 3);
    BAR();                               // readers done before buf reuse
  }
  WAITV(8);  BAR(); computeT((NT - 3) & 3); BAR();
  WAITV(4);  BAR(); computeT((NT - 2) & 3); BAR();
  WAITV(0);  BAR(); computeT((NT - 1) & 3);
  BAR();            // safe to reuse LDS for epilogue staging

  if (EPI == EPI_RESF32 || EPI == EPI_OUTB) {
    // fp32 output: direct stores are already full 64B lines
#pragma unroll
    for (int n = 0; n < 4; n++) {
      int gc2 = nBase + wn * 64 + n * 16 + l15;
      float bv = bias[gc2];
#pragma unroll
      for (int m = 0; m < 8; m++) {
#pragma unroll
        for (int j = 0; j < 4; j++) {
          int gr = mBase + wm * 128 + m * 16 + lr4 + j;
          size_t off = (size_t)gr * N + gc2;
          float v = acc[m][n][j] + bv;
          if (EPI == EPI_RESF32)
            outF[off] = v + ((const float*)res)[off];
          else
            outF[off] = v + b2f(((const unsigned short*)res)[off]);
        }
      }
    }
  } else {
    // bf16 output: stage per-wave 16x64 fp32 in LDS, read back row-contiguous,
    // write short4 (16 lanes x 8B = 128B full-line runs per row)
    float* ep = (float*)SM + wid * 1088;   // 4352 B/wave, row stride 68 floats
    int colc = nBase + wn * 64 + (lane & 15) * 4;
    f32x4 bias4 = {0.f, 0.f, 0.f, 0.f};
    if (EPI != EPI_BF16) bias4 = *(const f32x4*)&bias[colc];
#pragma unroll
    for (int m = 0; m < 8; m++) {
#pragma unroll
      for (int n = 0; n < 4; n++)
#pragma unroll
        for (int j = 0; j < 4; j++)
          ep[(lr4 + j) * 68 + n * 16 + l15] = acc[m][n][j];
      WAITL();
#pragma unroll
      for (int rd = 0; rd < 4; rd++) {
        int r = (lane >> 4) + 4 * rd;
        f32x4 v = *(const f32x4*)&ep[r * 68 + (lane & 15) * 4];
        v.x += bias4.x; v.y += bias4.y; v.z += bias4.z; v.w += bias4.w;
        int gr = mBase + wm * 128 + m * 16 + r;
        size_t off = (size_t)gr * N + colc;
        if (EPI == EPI_YB) {
          f32x4 rv = *(const f32x4*)&((const float*)res)[off];
          v.x += rv.x; v.y += rv.y; v.z += rv.z; v.w += rv.w;
        } else if (EPI == EPI_RELU_BF16) {
          v.x = fmaxf(v.x, 0.f); v.y = fmaxf(v.y, 0.f);
          v.z = fmaxf(v.z, 0.f); v.w = fmaxf(v.w, 0.f);
        }
        s16x4 o;
        o[0] = (short)f2b(v.x); o[1] = (short)f2b(v.y);
        o[2] = (short)f2b(v.z); o[3] = (short)f2b(v.w);
        *(s16x4*)(outB + off) = o;
      }
      WAITL();  // reads of m done before m+1 overwrites (per-wave region)
    }
  }
}

// ---------------- launch ----------------
extern "C" void kernel_launch(void* const* d_in, const int* in_sizes, int n_in,
                              void* d_out, int out_size, void* d_ws, size_t ws_size,
                              hipStream_t stream) {
  const float* x      = (const float*)d_in[0];
  const float* ln1_g  = (const float*)d_in[1];
  const float* ln1_b  = (const float*)d_in[2];
  const float* wq     = (const float*)d_in[3];
  const float* wk     = (const float*)d_in[4];
  const float* wv     = (const float*)d_in[5];
  const float* w_proj = (const float*)d_in[6];
  const float* b_proj = (const float*)d_in[7];
  const float* ln2_g  = (const float*)d_in[8];
  const float* ln2_b  = (const float*)d_in[9];
  const float* w1     = (const float*)d_in[10];
  const float* b1     = (const float*)d_in[11];
  const float* w2     = (const float*)d_in[12];
  const float* b2     = (const float*)d_in[13];
  float* out = (float*)d_out;

  char* ws = (char*)d_ws;
  unsigned short* qkvT  = (unsigned short*)(ws + 0);          // 1.5 MB
  unsigned short* projT = (unsigned short*)(ws + 1572864);    // 0.5 MB
  unsigned short* w1T   = (unsigned short*)(ws + 2097152);    // 2 MB
  unsigned short* w2T   = (unsigned short*)(ws + 4194304);    // 2 MB
  unsigned short* hbuf  = (unsigned short*)(ws + 6291456);    // 67 MB (h, then h2)
  unsigned short* qkv   = (unsigned short*)(ws + 73400320);   // 201 MB; reused as ff (268 MB)
  unsigned short* obuf  = (unsigned short*)(ws + 341835776);  // 67 MB
  unsigned short* ybuf  = (unsigned short*)(ws + 408944640);  // 67 MB (bf16 y) if room
  bool yb16 = ws_size >= 476053504ull;

  pack_qkv_k<<<3072, 256, 0, stream>>>(wq, wk, wv, qkvT);
  pack_T_k<<<1024, 256, 0, stream>>>(w_proj, projT, 512, 512);
  pack_T_k<<<4096, 256, 0, stream>>>(w1, w1T, 512, 2048);
  pack_T_k<<<4096, 256, 0, stream>>>(w2, w2T, 2048, 512);

  ln_k<<<16384, 256, 0, stream>>>(x, ln1_g, ln1_b, hbuf);

  // qkv = h @ [wq|wk|wv]  (M=65536, K=512, N=1536): 256 m-tiles x 6 n-tiles
  gemm_bt<EPI_BF16><<<1536, 512, 0, stream>>>(hbuf, qkvT, 512, 1536, 6,
                                              nullptr, nullptr, nullptr, qkv);
  attn_k<<<8192, 256, 0, stream>>>(qkv, obuf);

  unsigned short* ff = qkv;  // qkv dead after attn
  if (yb16) {
    // y(bf16) = o @ w_proj + b_proj + x   (N=512: 2 n-tiles)
    gemm_bt<EPI_YB><<<512, 512, 0, stream>>>(obuf, projT, 512, 512, 2,
                                             b_proj, x, nullptr, ybuf);
    ln_b_k<<<16384, 256, 0, stream>>>(ybuf, ln2_g, ln2_b, hbuf);
    gemm_bt<EPI_RELU_BF16><<<2048, 512, 0, stream>>>(hbuf, w1T, 512, 2048, 8,
                                                     b1, nullptr, nullptr, ff);
    // out(f32) = ff @ w2 + b2 + y(bf16)   (K=2048)
    gemm_bt<EPI_OUTB><<<512, 512, 0, stream>>>(ff, w2T, 2048, 512, 2,
                                               b2, ybuf, out, nullptr);
  } else {
    gemm_bt<EPI_RESF32><<<512, 512, 0, stream>>>(obuf, projT, 512, 512, 2,
                                                 b_proj, x, out, nullptr);
    ln_k<<<16384, 256, 0, stream>>>(out, ln2_g, ln2_b, hbuf);
    gemm_bt<EPI_RELU_BF16><<<2048, 512, 0, stream>>>(hbuf, w1T, 512, 2048, 8,
                                                     b1, nullptr, nullptr, ff);
    gemm_bt<EPI_RESF32><<<512, 512, 0, stream>>>(ff, w2T, 2048, 512, 2,
                                                 b2, out, out, nullptr);
  }
}

// Round 13
// 752.918 us; speedup vs baseline: 1.0474x; 1.0474x over previous
//
#include <hip/hip_runtime.h>
#include <hip/hip_bf16.h>

typedef __attribute__((ext_vector_type(8))) short s16x8;
typedef __attribute__((ext_vector_type(4))) short s16x4;
typedef __attribute__((ext_vector_type(4))) float f32x4;

#define GAS __attribute__((address_space(1)))
#define LAS __attribute__((address_space(3)))

#define WAITV(N) asm volatile("s_waitcnt vmcnt(" #N ")" ::: "memory")
#define WAITL() asm volatile("s_waitcnt lgkmcnt(0)" ::: "memory")
#define BAR() __builtin_amdgcn_s_barrier()
#define SCHED0() __builtin_amdgcn_sched_barrier(0)

__device__ __forceinline__ float b2f(unsigned short u) {
  union { unsigned int i; float f; } x; x.i = ((unsigned int)u) << 16; return x.f;
}
__device__ __forceinline__ unsigned short f2b(float f) {
  union { float f; unsigned int i; } x; x.f = f;
  unsigned int r = x.i + 0x7fffu + ((x.i >> 16) & 1u);
  return (unsigned short)(r >> 16);
}

// async global->LDS, 16B per lane; lds dest is wave-uniform base + lane*16
__device__ __forceinline__ void gl16(const unsigned short* g, unsigned short* l) {
  __builtin_amdgcn_global_load_lds((const GAS unsigned int*)g,
                                   (LAS unsigned int*)l, 16, 0, 0);
}

// ---------------- weight packing ----------------
__global__ __launch_bounds__(256) void pack_qkv_k(const float* __restrict__ wq,
                                                  const float* __restrict__ wk,
                                                  const float* __restrict__ wv,
                                                  unsigned short* __restrict__ dst) {
  int idx = blockIdx.x * 256 + threadIdx.x;   // n*512 + c
  int n = idx >> 9, c = idx & 511;
  int sel = n >> 9;
  int hn = n & 511;
  const float* src = sel == 0 ? wq : (sel == 1 ? wk : wv);
  float v = src[((hn >> 6) << 15) + (c << 6) + (hn & 63)];  // wq[h][c][d]
  dst[idx] = f2b(v);
}

// dst[n][k] = src[k][n], src is (K,N) row-major
__global__ __launch_bounds__(256) void pack_T_k(const float* __restrict__ src,
                                                unsigned short* __restrict__ dst,
                                                int K, int N) {
  int idx = blockIdx.x * 256 + threadIdx.x;
  int n = idx / K, k = idx % K;
  dst[idx] = f2b(src[(long long)k * N + n]);
}

// ---------------- layernorm (wave per row, C=512), fp32 input ----------------
__global__ __launch_bounds__(256) void ln_k(const float* __restrict__ in,
                                            const float* __restrict__ g,
                                            const float* __restrict__ bb,
                                            unsigned short* __restrict__ out) {
  int row = blockIdx.x * 4 + (threadIdx.x >> 6);
  int lane = threadIdx.x & 63;
  const float* p = in + (size_t)row * 512 + lane * 8;
  f32x4 a = *(const f32x4*)p;
  f32x4 b = *(const f32x4*)(p + 4);
  float vals[8] = {a.x, a.y, a.z, a.w, b.x, b.y, b.z, b.w};
  float s = 0.f, q = 0.f;
#pragma unroll
  for (int i = 0; i < 8; i++) { s += vals[i]; q += vals[i] * vals[i]; }
#pragma unroll
  for (int off = 1; off < 64; off <<= 1) {
    s += __shfl_xor(s, off);
    q += __shfl_xor(q, off);
  }
  float mean = s * (1.0f / 512.0f);
  float rstd = rsqrtf(q * (1.0f / 512.0f) - mean * mean + 1e-5f);
  const float* gp = g + lane * 8;
  const float* bp = bb + lane * 8;
  s16x8 o;
#pragma unroll
  for (int i = 0; i < 8; i++) o[i] = (short)f2b((vals[i] - mean) * rstd * gp[i] + bp[i]);
  *(s16x8*)(out + (size_t)row * 512 + lane * 8) = o;
}

// ---------------- layernorm, bf16 input ----------------
__global__ __launch_bounds__(256) void ln_b_k(const unsigned short* __restrict__ in,
                                              const float* __restrict__ g,
                                              const float* __restrict__ bb,
                                              unsigned short* __restrict__ out) {
  int row = blockIdx.x * 4 + (threadIdx.x >> 6);
  int lane = threadIdx.x & 63;
  s16x8 v8 = *(const s16x8*)(in + (size_t)row * 512 + lane * 8);
  float vals[8];
#pragma unroll
  for (int i = 0; i < 8; i++) vals[i] = b2f((unsigned short)v8[i]);
  float s = 0.f, q = 0.f;
#pragma unroll
  for (int i = 0; i < 8; i++) { s += vals[i]; q += vals[i] * vals[i]; }
#pragma unroll
  for (int off = 1; off < 64; off <<= 1) {
    s += __shfl_xor(s, off);
    q += __shfl_xor(q, off);
  }
  float mean = s * (1.0f / 512.0f);
  float rstd = rsqrtf(q * (1.0f / 512.0f) - mean * mean + 1e-5f);
  const float* gp = g + lane * 8;
  const float* bp = bb + lane * 8;
  s16x8 o;
#pragma unroll
  for (int i = 0; i < 8; i++) o[i] = (short)f2b((vals[i] - mean) * rstd * gp[i] + bp[i]);
  *(s16x8*)(out + (size_t)row * 512 + lane * 8) = o;
}

// ---------------- attention (one wave per (b,h); T=16, D=64) ----------------
__global__ __launch_bounds__(256) void attn_k(const unsigned short* __restrict__ qkv,
                                              unsigned short* __restrict__ o) {
  int w = (blockIdx.x << 2) + (threadIdx.x >> 6);
  int lane = threadIdx.x & 63;
  int b = w >> 3, h = w & 7;
  int t = lane >> 2, p = lane & 3;   // 4 lanes per query row, 16 d's each

  size_t rowq = (size_t)(b * 16 + t) * 1536 + h * 64 + p * 16;
  float q[16];
  {
    s16x8 q0 = *(const s16x8*)(qkv + rowq);
    s16x8 q1 = *(const s16x8*)(qkv + rowq + 8);
#pragma unroll
    for (int i = 0; i < 8; i++) {
      q[i] = b2f((unsigned short)q0[i]) * 0.125f;
      q[8 + i] = b2f((unsigned short)q1[i]) * 0.125f;
    }
  }
  float lg[16];
  size_t kbase = (size_t)(b * 16) * 1536 + 512 + h * 64 + p * 16;
#pragma unroll
  for (int s = 0; s < 16; s++) {
    const unsigned short* kp = qkv + kbase + (size_t)s * 1536;
    s16x8 k0 = *(const s16x8*)kp;
    s16x8 k1 = *(const s16x8*)(kp + 8);
    float d = 0.f;
#pragma unroll
    for (int i = 0; i < 8; i++)
      d += q[i] * b2f((unsigned short)k0[i]) + q[8 + i] * b2f((unsigned short)k1[i]);
    d += __shfl_xor(d, 1);
    d += __shfl_xor(d, 2);
    lg[s] = d;
  }
  float mx = -1e30f;
#pragma unroll
  for (int s = 0; s < 16; s++)
    if (s <= t) mx = fmaxf(mx, lg[s]);
  float den = 0.f;
#pragma unroll
  for (int s = 0; s < 16; s++) {
    float e = (s <= t) ? __expf(lg[s] - mx) : 0.f;
    lg[s] = e;
    den += e;
  }
  float inv = 1.f / den;
  float acc[16] = {};
  size_t vbase = kbase + 512;
#pragma unroll
  for (int s = 0; s < 16; s++) {
    const unsigned short* vp = qkv + vbase + (size_t)s * 1536;
    s16x8 v0 = *(const s16x8*)vp;
    s16x8 v1 = *(const s16x8*)(vp + 8);
    float a = lg[s] * inv;
#pragma unroll
    for (int i = 0; i < 8; i++) {
      acc[i] += a * b2f((unsigned short)v0[i]);
      acc[8 + i] += a * b2f((unsigned short)v1[i]);
    }
  }
  size_t orow = (size_t)(b * 16 + t) * 512 + h * 64 + p * 16;
  s16x8 r0, r1;
#pragma unroll
  for (int i = 0; i < 8; i++) {
    r0[i] = (short)f2b(acc[i]);
    r1[i] = (short)f2b(acc[8 + i]);
  }
  *(s16x8*)(o + orow) = r0;
  *(s16x8*)(o + orow + 8) = r1;
}

// ---------------- bf16 MFMA GEMM: 256x256 tile, BK=32, 8 waves, 8-phase-style ----------------
// T3+T4+T5 fine interleave (m201 template quantum): per K-tile, 2 phases of
//   {ds_read frags (8 or 4 x b128) | stage 2 gl16 | BAR | lgkmcnt(0)+sched_barrier |
//    setprio(1) 16 MFMA setprio(0) | BAR}
// 3 LDS buffers (96KB), prefetch distance 2 K-tiles: boundary WAITV(4) leaves
// t+2's 4 loads in flight (never 0 except 2-tile peeled tail); t+1's stages get
// a full K-tile (~1250cy) of hiding. Source-side XOR swizzle pair (0 conflicts).
// bf16 epilogues: LDS-staged full-line short4 stores (kills 2.3x write amp).
enum { EPI_BF16 = 0, EPI_RESF32 = 1, EPI_RELU_BF16 = 2, EPI_YB = 3, EPI_OUTB = 4 };

template <int EPI>
__global__ __launch_bounds__(512, 2) void gemm_bt(
    const unsigned short* __restrict__ A,   // (M, K) bf16
    const unsigned short* __restrict__ Bt,  // (N, K) bf16
    int K, int N, int nT,
    const float* __restrict__ bias, const void* __restrict__ res,
    float* __restrict__ outF, unsigned short* __restrict__ outB) {
  // buf b (b in 0..2): A at b*32768 bytes (256 rows x 32 cols bf16 = 16KB),
  // B at b*32768 + 16384. Total 96KB.
  __shared__ __align__(16) unsigned char SM[98304];

  int tid = threadIdx.x;
  // XCD-chunked 1D swizzle, N-fastest tile order (grids are multiples of 8)
  int lid = ((int)blockIdx.x & 7) * ((int)gridDim.x >> 3) + ((int)blockIdx.x >> 3);
  int mBase = (lid / nT) * 256;
  int nBase = (lid % nT) * 256;

  int lane = tid & 63;
  int wid = tid >> 6;     // 0..7
  int wm = wid >> 2;      // 0..1 -> A rows wm*128..
  int wn = wid & 3;       // 0..3 -> B rows wn*64..
  int l15 = lane & 15;
  int s4 = lane >> 4;     // 0..3
  int lr4 = s4 * 4;
  int fc = ((s4 ^ ((l15 >> 1) & 3)) << 3);   // swizzled 8-elem slot for ds_read

  // staging: thread covers row tid>>2 (0..127), phys 16B slot tid&3;
  // source col pre-swizzled: LDS[r][p] = G[r][p ^ ((r>>1)&3)]
  int srow = tid >> 2;
  int scol = (((tid & 3) ^ ((tid >> 3) & 3)) << 3);
  const unsigned short* pa = A + (size_t)(mBase + srow) * K + scol;
  const unsigned short* pb = Bt + (size_t)(nBase + srow) * K + scol;
  size_t k128 = (size_t)128 * K;

  f32x4 acc[8][4] = {};

  auto stageFull = [&](int buf, int kt) {   // prologue: 4 gl16 = one 256x32 A + B tile
    unsigned short* dA = (unsigned short*)(SM + buf * 32768) + wid * 512;
    unsigned short* dB = (unsigned short*)(SM + buf * 32768 + 16384) + wid * 512;
    gl16(pa + kt, dA);
    gl16(pa + kt + k128, dA + 4096);
    gl16(pb + kt, dB);
    gl16(pb + kt + k128, dB + 4096);
  };

  // one K-tile = 2 phases; optionally stages tile (in sbuf, global col kt2)
  auto tileBody = [&](int buf, int stg, int sbuf, int kt2) {
    const unsigned short* hA = (const unsigned short*)(SM + buf * 32768) + wm * 4096;
    const unsigned short* hB = (const unsigned short*)(SM + buf * 32768 + 16384) + wn * 2048;
    s16x8 bfr[4], afr[4];
    // ---- phase 0: B frags + A m0-3; stage A half of tile t+2 ----
#pragma unroll
    for (int n = 0; n < 4; ++n)
      bfr[n] = *(const s16x8*)&hB[(n * 16 + l15) * 32 + fc];
#pragma unroll
    for (int m = 0; m < 4; ++m)
      afr[m] = *(const s16x8*)&hA[(m * 16 + l15) * 32 + fc];
    if (stg) {
      unsigned short* dA = (unsigned short*)(SM + sbuf * 32768) + wid * 512;
      gl16(pa + kt2, dA);
      gl16(pa + kt2 + k128, dA + 4096);
    }
    BAR();
    WAITL(); SCHED0();
    __builtin_amdgcn_s_setprio(1);
#pragma unroll
    for (int m = 0; m < 4; ++m)
#pragma unroll
      for (int n = 0; n < 4; ++n)
        acc[m][n] = __builtin_amdgcn_mfma_f32_16x16x32_bf16(afr[m], bfr[n], acc[m][n], 0, 0, 0);
    __builtin_amdgcn_s_setprio(0);
    BAR();
    // ---- phase 1: A m4-7 (B reused); stage B half of tile t+2 ----
#pragma unroll
    for (int m = 0; m < 4; ++m)
      afr[m] = *(const s16x8*)&hA[((m + 4) * 16 + l15) * 32 + fc];
    if (stg) {
      unsigned short* dB = (unsigned short*)(SM + sbuf * 32768 + 16384) + wid * 512;
      gl16(pb + kt2, dB);
      gl16(pb + kt2 + k128, dB + 4096);
    }
    BAR();
    WAITL(); SCHED0();
    __builtin_amdgcn_s_setprio(1);
#pragma unroll
    for (int m = 0; m < 4; ++m)
#pragma unroll
      for (int n = 0; n < 4; ++n)
        acc[m + 4][n] = __builtin_amdgcn_mfma_f32_16x16x32_bf16(afr[m], bfr[n], acc[m + 4][n], 0, 0, 0);
    __builtin_amdgcn_s_setprio(0);
    BAR();
  };

  int NT = K >> 5;   // >= 16 for all our shapes
  stageFull(0, 0);
  stageFull(1, 32);
  WAITV(4);          // tile 0 landed; tile 1 in flight
  BAR();
  int t = 0;
  int b0 = 0, b1 = 1, b2 = 2;   // rotating buffer ids (avoid % in loop)
  for (; t < NT - 2; ++t) {
    tileBody(b0, 1, b2, (t + 2) << 5);
    WAITV(4);        // tile t+1 landed (t+2's 4 loads stay in flight)
    BAR();
    int tmp = b0; b0 = b1; b1 = b2; b2 = tmp;
  }
  tileBody(b0, 0, 0, 0);   // t = NT-2, no stage
  WAITV(0);                // tail: tile NT-1's loads must land
  BAR();
  tileBody(b1, 0, 0, 0);   // t = NT-1
  BAR();                   // safe to reuse LDS for epilogue staging

  if (EPI == EPI_RESF32 || EPI == EPI_OUTB) {
    // fp32 output: direct stores are already full 64B lines
#pragma unroll
    for (int n = 0; n < 4; n++) {
      int gc2 = nBase + wn * 64 + n * 16 + l15;
      float bv = bias[gc2];
#pragma unroll
      for (int m = 0; m < 8; m++) {
#pragma unroll
        for (int j = 0; j < 4; j++) {
          int gr = mBase + wm * 128 + m * 16 + lr4 + j;
          size_t off = (size_t)gr * N + gc2;
          float v = acc[m][n][j] + bv;
          if (EPI == EPI_RESF32)
            outF[off] = v + ((const float*)res)[off];
          else
            outF[off] = v + b2f(((const unsigned short*)res)[off]);
        }
      }
    }
  } else {
    // bf16 output: stage per-wave 16x64 fp32 in LDS, read back row-contiguous,
    // write short4 (16 lanes x 8B = 128B full-line runs per row)
    float* ep = (float*)SM + wid * 1088;   // 4352 B/wave, row stride 68 floats
    int colc = nBase + wn * 64 + (lane & 15) * 4;
    f32x4 bias4 = {0.f, 0.f, 0.f, 0.f};
    if (EPI != EPI_BF16) bias4 = *(const f32x4*)&bias[colc];
#pragma unroll
    for (int m = 0; m < 8; m++) {
#pragma unroll
      for (int n = 0; n < 4; n++)
#pragma unroll
        for (int j = 0; j < 4; j++)
          ep[(lr4 + j) * 68 + n * 16 + l15] = acc[m][n][j];
      WAITL();
#pragma unroll
      for (int rd = 0; rd < 4; rd++) {
        int r = (lane >> 4) + 4 * rd;
        f32x4 v = *(const f32x4*)&ep[r * 68 + (lane & 15) * 4];
        v.x += bias4.x; v.y += bias4.y; v.z += bias4.z; v.w += bias4.w;
        int gr = mBase + wm * 128 + m * 16 + r;
        size_t off = (size_t)gr * N + colc;
        if (EPI == EPI_YB) {
          f32x4 rv = *(const f32x4*)&((const float*)res)[off];
          v.x += rv.x; v.y += rv.y; v.z += rv.z; v.w += rv.w;
        } else if (EPI == EPI_RELU_BF16) {
          v.x = fmaxf(v.x, 0.f); v.y = fmaxf(v.y, 0.f);
          v.z = fmaxf(v.z, 0.f); v.w = fmaxf(v.w, 0.f);
        }
        s16x4 o;
        o[0] = (short)f2b(v.x); o[1] = (short)f2b(v.y);
        o[2] = (short)f2b(v.z); o[3] = (short)f2b(v.w);
        *(s16x4*)(outB + off) = o;
      }
      WAITL();  // reads of m done before m+1 overwrites (per-wave region)
    }
  }
}

// ---------------- launch ----------------
extern "C" void kernel_launch(void* const* d_in, const int* in_sizes, int n_in,
                              void* d_out, int out_size, void* d_ws, size_t ws_size,
                              hipStream_t stream) {
  const float* x      = (const float*)d_in[0];
  const float* ln1_g  = (const float*)d_in[1];
  const float* ln1_b  = (const float*)d_in[2];
  const float* wq     = (const float*)d_in[3];
  const float* wk     = (const float*)d_in[4];
  const float* wv     = (const float*)d_in[5];
  const float* w_proj = (const float*)d_in[6];
  const float* b_proj = (const float*)d_in[7];
  const float* ln2_g  = (const float*)d_in[8];
  const float* ln2_b  = (const float*)d_in[9];
  const float* w1     = (const float*)d_in[10];
  const float* b1     = (const float*)d_in[11];
  const float* w2     = (const float*)d_in[12];
  const float* b2     = (const float*)d_in[13];
  float* out = (float*)d_out;

  char* ws = (char*)d_ws;
  unsigned short* qkvT  = (unsigned short*)(ws + 0);          // 1.5 MB
  unsigned short* projT = (unsigned short*)(ws + 1572864);    // 0.5 MB
  unsigned short* w1T   = (unsigned short*)(ws + 2097152);    // 2 MB
  unsigned short* w2T   = (unsigned short*)(ws + 4194304);    // 2 MB
  unsigned short* hbuf  = (unsigned short*)(ws + 6291456);    // 67 MB (h, then h2)
  unsigned short* qkv   = (unsigned short*)(ws + 73400320);   // 201 MB; reused as ff (268 MB)
  unsigned short* obuf  = (unsigned short*)(ws + 341835776);  // 67 MB
  unsigned short* ybuf  = (unsigned short*)(ws + 408944640);  // 67 MB (bf16 y) if room
  bool yb16 = ws_size >= 476053504ull;

  pack_qkv_k<<<3072, 256, 0, stream>>>(wq, wk, wv, qkvT);
  pack_T_k<<<1024, 256, 0, stream>>>(w_proj, projT, 512, 512);
  pack_T_k<<<4096, 256, 0, stream>>>(w1, w1T, 512, 2048);
  pack_T_k<<<4096, 256, 0, stream>>>(w2, w2T, 2048, 512);

  ln_k<<<16384, 256, 0, stream>>>(x, ln1_g, ln1_b, hbuf);

  // qkv = h @ [wq|wk|wv]  (M=65536, K=512, N=1536): 256 m-tiles x 6 n-tiles
  gemm_bt<EPI_BF16><<<1536, 512, 0, stream>>>(hbuf, qkvT, 512, 1536, 6,
                                              nullptr, nullptr, nullptr, qkv);
  attn_k<<<8192, 256, 0, stream>>>(qkv, obuf);

  unsigned short* ff = qkv;  // qkv dead after attn
  if (yb16) {
    // y(bf16) = o @ w_proj + b_proj + x   (N=512: 2 n-tiles)
    gemm_bt<EPI_YB><<<512, 512, 0, stream>>>(obuf, projT, 512, 512, 2,
                                             b_proj, x, nullptr, ybuf);
    ln_b_k<<<16384, 256, 0, stream>>>(ybuf, ln2_g, ln2_b, hbuf);
    gemm_bt<EPI_RELU_BF16><<<2048, 512, 0, stream>>>(hbuf, w1T, 512, 2048, 8,
                                                     b1, nullptr, nullptr, ff);
    // out(f32) = ff @ w2 + b2 + y(bf16)   (K=2048)
    gemm_bt<EPI_OUTB><<<512, 512, 0, stream>>>(ff, w2T, 2048, 512, 2,
                                               b2, ybuf, out, nullptr);
  } else {
    gemm_bt<EPI_RESF32><<<512, 512, 0, stream>>>(obuf, projT, 512, 512, 2,
                                                 b_proj, x, out, nullptr);
    ln_k<<<16384, 256, 0, stream>>>(out, ln2_g, ln2_b, hbuf);
    gemm_bt<EPI_RELU_BF16><<<2048, 512, 0, stream>>>(hbuf, w1T, 512, 2048, 8,
                                                     b1, nullptr, nullptr, ff);
    gemm_bt<EPI_RESF32><<<512, 512, 0, stream>>>(ff, w2T, 2048, 512, 2,
                                                 b2, out, out, nullptr);
  }
}